// Round 1
// 866.688 us; speedup vs baseline: 1.0247x; 1.0247x over previous
//
#include <hip/hip_runtime.h>

#define DEV __device__ __forceinline__

typedef __attribute__((ext_vector_type(4))) float f32x4;
typedef __attribute__((ext_vector_type(8))) __bf16 bf16x8;

static constexpr int Bc = 256;      // batch
static constexpr int Sc = 200;      // seq
static constexpr int Hc = 64;       // hidden
static constexpr int Ec = 768;      // emb
static constexpr int HDc = 32;      // head dim
static constexpr int NROWS = Bc * Sc;   // 51200

// ---------- helpers ----------
DEV __bf16 f2bf(float f) {
    unsigned u = __builtin_bit_cast(unsigned, f);
    unsigned short s = (unsigned short)((u + 0x7fffu + ((u >> 16) & 1u)) >> 16);  // RNE
    return __builtin_bit_cast(__bf16, s);
}
DEV float bf2f(__bf16 h) {
    unsigned short s = __builtin_bit_cast(unsigned short, h);
    unsigned u = ((unsigned)s) << 16;
    return __builtin_bit_cast(float, u);
}
DEV bf16x8 ld8(const __bf16* p) { return *(const bf16x8*)p; }

// 8 consecutive fp32 -> bf16x8 fragment
DEV bf16x8 cvt8(const float* __restrict__ p) {
    f32x4 a = *(const f32x4*)p;
    f32x4 b = *(const f32x4*)(p + 4);
    bf16x8 r;
    r[0] = f2bf(a[0]); r[1] = f2bf(a[1]); r[2] = f2bf(a[2]); r[3] = f2bf(a[3]);
    r[4] = f2bf(b[0]); r[5] = f2bf(b[1]); r[6] = f2bf(b[2]); r[7] = f2bf(b[3]);
    return r;
}

// 64x64 GEMM tile: Y[m0..m0+15][:] = A(16x64) @ W^T-layout(bf16 [n][k]) + bias
DEV void gemm64(bf16x8 A0, bf16x8 A1, const __bf16* __restrict__ W,
                const float* __restrict__ bias, __bf16* __restrict__ Y,
                int m0, int ln, int quad, int maxrow)
{
#pragma unroll
    for (int nt = 0; nt < 4; nt++) {
        int col = nt * 16 + ln;
        bf16x8 w0 = ld8(W + col * 64 + quad * 8);
        bf16x8 w1 = ld8(W + col * 64 + 32 + quad * 8);
        f32x4 acc = (f32x4){0.f, 0.f, 0.f, 0.f};
        acc = __builtin_amdgcn_mfma_f32_16x16x32_bf16(A0, w0, acc, 0, 0, 0);
        acc = __builtin_amdgcn_mfma_f32_16x16x32_bf16(A1, w1, acc, 0, 0, 0);
        float bv = bias[col];
#pragma unroll
        for (int reg = 0; reg < 4; reg++) {
            int r = m0 + quad * 4 + reg;
            if (r < maxrow) Y[(long)r * 64 + col] = f2bf(acc[reg] + bv);
        }
    }
}

// ---------- one-shot weight transpose + bf16 convert ----------
// featW [768][64] -> featWt [64][768];  10 x [2][64][64] -> Wt[mat][l][n][k]
__global__ __launch_bounds__(256) void wconv_kernel(
    const float* __restrict__ featW,
    const float* __restrict__ Wq, const float* __restrict__ Wk, const float* __restrict__ Wv,
    const float* __restrict__ Wpq, const float* __restrict__ Wpk,
    const float* __restrict__ Wfq, const float* __restrict__ Wfk,
    const float* __restrict__ Wo, const float* __restrict__ W1, const float* __restrict__ W2,
    __bf16* __restrict__ featWt, __bf16* __restrict__ Wt)
{
    int gid = blockIdx.x * 256 + threadIdx.x;
    if (gid < Ec * Hc) {
        int k = gid >> 6, n = gid & 63;
        featWt[n * Ec + k] = f2bf(featW[gid]);
        return;
    }
    int e2 = gid - Ec * Hc;                 // 0 .. 81919
    // mat is uniform per 256-thread block (8192 % 256 == 0): keep it scalar
    int mat = __builtin_amdgcn_readfirstlane(e2 >> 13);
    int r = e2 & 8191, l = r >> 12, e = r & 4095, k = e >> 6, n = e & 63;
    const float* Ws[10] = {Wq, Wk, Wv, Wpq, Wpk, Wfq, Wfk, Wo, W1, W2};
    const float* W = Ws[mat];
    Wt[mat * 8192 + l * 4096 + n * 64 + k] = f2bf(W[l * 4096 + e]);
}

// ---------- feat = LN((rev[t]+meta[t]) @ featW + featb), bf16 out ----------
// also fused: q = item_emb[t] * (t != 0)   (was qinit_kernel)
__global__ __launch_bounds__(256) void feat_kernel(
    const int* __restrict__ tseq, const float* __restrict__ rev,
    const float* __restrict__ meta, const __bf16* __restrict__ featWt,
    const float* __restrict__ featb, const float* __restrict__ g,
    const float* __restrict__ bb, const float* __restrict__ item,
    __bf16* __restrict__ out, __bf16* __restrict__ qout)
{
    int lane = threadIdx.x & 63, wv = threadIdx.x >> 6;
    int ln = lane & 15, quad = lane >> 4;
    int m0 = blockIdx.x * 64 + wv * 16;
    long t = tseq[m0 + ln];

    // ---- fused qinit: row m0+ln, cols quad*16 .. quad*16+16 ----
    {
        const float* ip = item + t * Hc + quad * 16;
        f32x4 v0 = *(const f32x4*)ip;
        f32x4 v1 = *(const f32x4*)(ip + 4);
        f32x4 v2 = *(const f32x4*)(ip + 8);
        f32x4 v3 = *(const f32x4*)(ip + 12);
        float kf = (t != 0) ? 1.f : 0.f;
        bf16x8 o0, o1;
        o0[0] = f2bf(v0[0] * kf); o0[1] = f2bf(v0[1] * kf); o0[2] = f2bf(v0[2] * kf); o0[3] = f2bf(v0[3] * kf);
        o0[4] = f2bf(v1[0] * kf); o0[5] = f2bf(v1[1] * kf); o0[6] = f2bf(v1[2] * kf); o0[7] = f2bf(v1[3] * kf);
        o1[0] = f2bf(v2[0] * kf); o1[1] = f2bf(v2[1] * kf); o1[2] = f2bf(v2[2] * kf); o1[3] = f2bf(v2[3] * kf);
        o1[4] = f2bf(v3[0] * kf); o1[5] = f2bf(v3[1] * kf); o1[6] = f2bf(v3[2] * kf); o1[7] = f2bf(v3[3] * kf);
        *(bf16x8*)(qout + (long)(m0 + ln) * Hc + quad * 16) = o0;
        *(bf16x8*)(qout + (long)(m0 + ln) * Hc + quad * 16 + 8) = o1;
    }

    const float* rp = rev + t * Ec + quad * 8;
    const float* mp = meta + t * Ec + quad * 8;

    f32x4 acc[4];
#pragma unroll
    for (int nt = 0; nt < 4; nt++) acc[nt] = (f32x4){0.f, 0.f, 0.f, 0.f};

    // depth-1 software pipeline: prefetch next A chunk (HBM gather) and next
    // B fragments (L2-hot weights) while the current MFMAs run.
    f32x4 ra = *(const f32x4*)rp;
    f32x4 rb = *(const f32x4*)(rp + 4);
    f32x4 ma = *(const f32x4*)mp;
    f32x4 mb = *(const f32x4*)(mp + 4);
    bf16x8 bw[4];
#pragma unroll
    for (int nt = 0; nt < 4; nt++) bw[nt] = ld8(featWt + (nt * 16 + ln) * Ec + quad * 8);

    for (int ks = 0; ks < Ec / 32; ks++) {
        f32x4 nra = ra, nrb = rb, nma = ma, nmb = mb;
        bf16x8 nbw[4];
#pragma unroll
        for (int nt = 0; nt < 4; nt++) nbw[nt] = bw[nt];
        if (ks < Ec / 32 - 1) {
            nra = *(const f32x4*)(rp + (ks + 1) * 32);
            nrb = *(const f32x4*)(rp + (ks + 1) * 32 + 4);
            nma = *(const f32x4*)(mp + (ks + 1) * 32);
            nmb = *(const f32x4*)(mp + (ks + 1) * 32 + 4);
#pragma unroll
            for (int nt = 0; nt < 4; nt++)
                nbw[nt] = ld8(featWt + (nt * 16 + ln) * Ec + (ks + 1) * 32 + quad * 8);
        }
        bf16x8 a;
        a[0] = f2bf(ra[0] + ma[0]); a[1] = f2bf(ra[1] + ma[1]);
        a[2] = f2bf(ra[2] + ma[2]); a[3] = f2bf(ra[3] + ma[3]);
        a[4] = f2bf(rb[0] + mb[0]); a[5] = f2bf(rb[1] + mb[1]);
        a[6] = f2bf(rb[2] + mb[2]); a[7] = f2bf(rb[3] + mb[3]);
#pragma unroll
        for (int nt = 0; nt < 4; nt++)
            acc[nt] = __builtin_amdgcn_mfma_f32_16x16x32_bf16(a, bw[nt], acc[nt], 0, 0, 0);
        ra = nra; rb = nrb; ma = nma; mb = nmb;
#pragma unroll
        for (int nt = 0; nt < 4; nt++) bw[nt] = nbw[nt];
    }
#pragma unroll
    for (int reg = 0; reg < 4; reg++) {
        float vals[4]; float s = 0.f, s2 = 0.f;
#pragma unroll
        for (int nt = 0; nt < 4; nt++) {
            float v = acc[nt][reg] + featb[nt * 16 + ln];
            vals[nt] = v; s += v; s2 += v * v;
        }
#pragma unroll
        for (int m = 1; m <= 8; m <<= 1) { s += __shfl_xor(s, m, 64); s2 += __shfl_xor(s2, m, 64); }
        float mean = s * (1.f / 64.f);
        float var = s2 * (1.f / 64.f) - mean * mean;
        float inv = rsqrtf(var + 1e-5f);
        int r = m0 + quad * 4 + reg;
#pragma unroll
        for (int nt = 0; nt < 4; nt++) {
            int c = nt * 16 + ln;
            out[(long)r * Hc + c] = f2bf((vals[nt] - mean) * inv * g[c] + bb[c]);
        }
    }
}

// ---------- pe projections for both layers: pq/pk = pe @ Wp* + b ----------
__global__ __launch_bounds__(256) void pe_kernel(
    const float* __restrict__ pe, const __bf16* __restrict__ Wt,
    const float* __restrict__ bpq, const float* __restrict__ bpk,
    __bf16* __restrict__ pqp, __bf16* __restrict__ pkp)
{
    int l = blockIdx.x >> 2, rb = blockIdx.x & 3;
    int lane = threadIdx.x & 63, wv = threadIdx.x >> 6;
    int ln = lane & 15, quad = lane >> 4;
    int m0 = rb * 64 + wv * 16;
    int arow = m0 + ln; if (arow > Sc - 1) arow = Sc - 1;
    bf16x8 a0 = cvt8(pe + arow * Hc + quad * 8);
    bf16x8 a1 = cvt8(pe + arow * Hc + 32 + quad * 8);
    gemm64(a0, a1, Wt + 3 * 8192 + l * 4096, bpq + l * 64, pqp + l * Sc * Hc, m0, ln, quad, Sc);
    gemm64(a0, a1, Wt + 4 * 8192 + l * 4096, bpk + l * 64, pkp + l * Sc * Hc, m0, ln, quad, Sc);
}

// ---------- fused: Qn = LN(q); 5 projections q/k/v/fq/fk ----------
__global__ __launch_bounds__(256) void qkvf_kernel(
    const __bf16* __restrict__ q, const __bf16* __restrict__ feat,
    const __bf16* __restrict__ Wt, int layer,
    const float* __restrict__ bq, const float* __restrict__ bk, const float* __restrict__ bv,
    const float* __restrict__ bfq, const float* __restrict__ bfk,
    const float* __restrict__ ag, const float* __restrict__ ab,
    __bf16* __restrict__ Qn, __bf16* __restrict__ qp, __bf16* __restrict__ kp,
    __bf16* __restrict__ vp, __bf16* __restrict__ fqp, __bf16* __restrict__ fkp)
{
    int lane = threadIdx.x & 63, wv = threadIdx.x >> 6;
    int ln = lane & 15, quad = lane >> 4;
    int m0 = blockIdx.x * 64 + wv * 16;
    long row = m0 + ln;
    bf16x8 aq0 = ld8(q + row * 64 + quad * 8);
    bf16x8 aq1 = ld8(q + row * 64 + 32 + quad * 8);
    bf16x8 af0 = ld8(feat + row * 64 + quad * 8);
    bf16x8 af1 = ld8(feat + row * 64 + 32 + quad * 8);

    // LN over the row (lane holds 16 of row ln's 64 elems; partners differ in bits 4,5)
    float s = 0.f, s2 = 0.f;
#pragma unroll
    for (int j = 0; j < 8; j++) {
        float v = bf2f(aq0[j]); s += v; s2 += v * v;
        v = bf2f(aq1[j]); s += v; s2 += v * v;
    }
    s += __shfl_xor(s, 16, 64); s += __shfl_xor(s, 32, 64);
    s2 += __shfl_xor(s2, 16, 64); s2 += __shfl_xor(s2, 32, 64);
    float mean = s * (1.f / 64.f);
    float inv = rsqrtf(s2 * (1.f / 64.f) - mean * mean + 1e-8f);
    const float* agl = ag + layer * 64; const float* abl = ab + layer * 64;
    bf16x8 nq0, nq1;
#pragma unroll
    for (int j = 0; j < 8; j++) {
        int k0 = quad * 8 + j, k1 = 32 + quad * 8 + j;
        nq0[j] = f2bf((bf2f(aq0[j]) - mean) * inv * agl[k0] + abl[k0]);
        nq1[j] = f2bf((bf2f(aq1[j]) - mean) * inv * agl[k1] + abl[k1]);
    }
    *(bf16x8*)(Qn + row * 64 + quad * 8) = nq0;
    *(bf16x8*)(Qn + row * 64 + 32 + quad * 8) = nq1;

    gemm64(nq0, nq1, Wt + 0 * 8192 + layer * 4096, bq + layer * 64, qp, m0, ln, quad, NROWS);
    gemm64(aq0, aq1, Wt + 1 * 8192 + layer * 4096, bk + layer * 64, kp, m0, ln, quad, NROWS);
    gemm64(aq0, aq1, Wt + 2 * 8192 + layer * 4096, bv + layer * 64, vp, m0, ln, quad, NROWS);
    gemm64(af0, af1, Wt + 5 * 8192 + layer * 4096, bfq + layer * 64, fqp, m0, ln, quad, NROWS);
    gemm64(af0, af1, Wt + 6 * 8192 + layer * 4096, bfk + layer * 64, fkp, m0, ln, quad, NROWS);
}

// ---------- attention per (b, head, t-chunk) ----------
// blockIdx.x = b*2+h ; blockIdx.y = c in [0,7): chunk handles query tiles {c, 12-c}
// (balanced: (c+1)+(13-c) = 14 tile-units per chunk; c==6 does tile 6 only).
// Query tiles are independent; K/V/P state is block-local, so t-parallelism is safe.
// ctx aliases qp: tile t's Q rows are read only by the chunk that owns tile t,
// strictly before that chunk writes the same rows.
__global__ __launch_bounds__(256) void attn_kernel(
    const __bf16* __restrict__ qp, const __bf16* __restrict__ kp, const __bf16* __restrict__ vp,
    const __bf16* __restrict__ pqp, const __bf16* __restrict__ pkp,
    const __bf16* __restrict__ fqp, const __bf16* __restrict__ fkp,
    __bf16* __restrict__ ctx)
{
    __shared__ float Sm[16 * 208];        // score tile; P (bf16) overlays same rows
    __shared__ __bf16 Vt[32 * 224];       // V transposed [vdim][key], key-padded

    int bb = blockIdx.x >> 1, h = blockIdx.x & 1;
    int c = blockIdx.y;
    int tid = threadIdx.x;
    int lane = tid & 63, wv = tid >> 6;
    int ln = lane & 15, quad = lane >> 4;
    const int hc = h * HDc;
    const long base = (long)bb * Sc;
    const float scale = 0.17677669529663687f;   // 1/sqrt(32)
    __bf16* P = (__bf16*)Sm;                    // row stride 416 bf16 (= 832 B)

    int tmax = 12 - c;
    int KV = tmax * 16 + 16; if (KV > Sc) KV = Sc;   // keys this chunk needs
    for (int idx = tid; idx < KV * 32; idx += 256) {
        int k = idx >> 5, n = idx & 31;
        Vt[n * 224 + k] = vp[(base + k) * Hc + hc + n];
    }
    for (int idx = tid; idx < (224 - KV) * 32; idx += 256) {
        int k = KV + (idx >> 5), n = idx & 31;
        Vt[n * 224 + k] = __builtin_bit_cast(__bf16, (unsigned short)0);
    }

    int nstep = (c == 6) ? 1 : 2;
    for (int step = 0; step < nstep; step++) {
        int t = step ? tmax : c;
        __syncthreads();
        int arow = t * 16 + ln; if (arow > Sc - 1) arow = Sc - 1;
        bf16x8 aq0 = ld8(qp + (base + arow) * Hc + hc + quad * 8);
        bf16x8 aq1 = ld8(pqp + (long)arow * Hc + hc + quad * 8);
        bf16x8 aq2 = ld8(fqp + (base + arow) * Hc + hc + quad * 8);
        for (int nt = wv; nt <= t; nt += 4) {
            int key = nt * 16 + ln; if (key > Sc - 1) key = Sc - 1;
            f32x4 acc = (f32x4){0.f, 0.f, 0.f, 0.f};
            acc = __builtin_amdgcn_mfma_f32_16x16x32_bf16(aq0, ld8(kp + (base + key) * Hc + hc + quad * 8), acc, 0, 0, 0);
            acc = __builtin_amdgcn_mfma_f32_16x16x32_bf16(aq1, ld8(pkp + (long)key * Hc + hc + quad * 8), acc, 0, 0, 0);
            acc = __builtin_amdgcn_mfma_f32_16x16x32_bf16(aq2, ld8(fkp + (base + key) * Hc + hc + quad * 8), acc, 0, 0, 0);
#pragma unroll
            for (int reg = 0; reg < 4; reg++)
                Sm[(quad * 4 + reg) * 208 + nt * 16 + ln] = acc[reg] * scale;
        }
        __syncthreads();
        for (int ri = 0; ri < 4; ri++) {
            int r = wv * 4 + ri;
            int qrow = t * 16 + r;
            float sv[4]; float mx = -1e30f;
#pragma unroll
            for (int j = 0; j < 4; j++) {
                int k = lane + 64 * j;
                sv[j] = (k <= qrow && k < 208) ? Sm[r * 208 + k] : -1e30f;
                mx = fmaxf(mx, sv[j]);
            }
#pragma unroll
            for (int m = 1; m <= 32; m <<= 1) mx = fmaxf(mx, __shfl_xor(mx, m, 64));
            float sum = 0.f; float pv[4];
#pragma unroll
            for (int j = 0; j < 4; j++) {
                float e = (sv[j] > -1e29f) ? __expf(sv[j] - mx) : 0.f;
                pv[j] = e; sum += e;
            }
#pragma unroll
            for (int m = 1; m <= 32; m <<= 1) sum += __shfl_xor(sum, m, 64);
            float inv = 1.f / sum;
#pragma unroll
            for (int j = 0; j < 4; j++) {
                int k = lane + 64 * j;
                if (k < 224) P[r * 416 + k] = f2bf(pv[j] * inv);
            }
        }
        __syncthreads();
        if (wv < 2) {
            int ksteps = (t + 2) >> 1;
            f32x4 acc = (f32x4){0.f, 0.f, 0.f, 0.f};
            const char* Pb = (const char*)Sm;
            for (int ks = 0; ks < ksteps; ks++) {
                bf16x8 pa = *(const bf16x8*)(Pb + ln * 832 + ks * 64 + quad * 16);
                bf16x8 vb = *(const bf16x8*)(&Vt[(wv * 16 + ln) * 224 + ks * 32 + quad * 8]);
                acc = __builtin_amdgcn_mfma_f32_16x16x32_bf16(pa, vb, acc, 0, 0, 0);
            }
#pragma unroll
            for (int reg = 0; reg < 4; reg++) {
                int r = t * 16 + quad * 4 + reg;
                if (r < Sc) ctx[(base + r) * Hc + hc + wv * 16 + ln] = f2bf(acc[reg]);
            }
        }
    }
}

// ---------- fused: t = ctx@Wo+bo+Qn; u = LN(t); q = relu(u@W1+b1)@W2+b2+u; q *= keep ----------
__global__ __launch_bounds__(256) void ffn_kernel(
    const __bf16* __restrict__ ctx, const __bf16* __restrict__ Qn,
    const __bf16* __restrict__ WtO, const __bf16* __restrict__ Wt1, const __bf16* __restrict__ Wt2,
    const float* __restrict__ bo, const float* __restrict__ b1, const float* __restrict__ b2,
    const float* __restrict__ fg, const float* __restrict__ fb,
    const int* __restrict__ tseq, __bf16* __restrict__ qout)
{
    __shared__ __bf16 T1[4][16 * 64];
    __shared__ __bf16 T2[4][16 * 64];
    int lane = threadIdx.x & 63, wv = threadIdx.x >> 6;
    int ln = lane & 15, quad = lane >> 4;
    int m0 = blockIdx.x * 64 + wv * 16;

    bf16x8 ac0 = ld8(ctx + (long)(m0 + ln) * 64 + quad * 8);
    bf16x8 ac1 = ld8(ctx + (long)(m0 + ln) * 64 + 32 + quad * 8);

    float tv[16];
#pragma unroll
    for (int nt = 0; nt < 4; nt++) {
        int col = nt * 16 + ln;
        bf16x8 w0 = ld8(WtO + col * 64 + quad * 8);
        bf16x8 w1 = ld8(WtO + col * 64 + 32 + quad * 8);
        f32x4 acc = (f32x4){0.f, 0.f, 0.f, 0.f};
        acc = __builtin_amdgcn_mfma_f32_16x16x32_bf16(ac0, w0, acc, 0, 0, 0);
        acc = __builtin_amdgcn_mfma_f32_16x16x32_bf16(ac1, w1, acc, 0, 0, 0);
        float bov = bo[col];
#pragma unroll
        for (int reg = 0; reg < 4; reg++)
            tv[nt * 4 + reg] = acc[reg] + bov + bf2f(Qn[(long)(m0 + quad * 4 + reg) * 64 + col]);
    }
    // LN in D-layout: row quad*4+reg lives on the 16 lanes sharing this quad
    float s[4] = {0, 0, 0, 0}, s2[4] = {0, 0, 0, 0};
#pragma unroll
    for (int reg = 0; reg < 4; reg++)
#pragma unroll
        for (int nt = 0; nt < 4; nt++) { float v = tv[nt * 4 + reg]; s[reg] += v; s2[reg] += v * v; }
#pragma unroll
    for (int m = 1; m <= 8; m <<= 1)
#pragma unroll
        for (int reg = 0; reg < 4; reg++) { s[reg] += __shfl_xor(s[reg], m, 64); s2[reg] += __shfl_xor(s2[reg], m, 64); }
    float uv[16];
#pragma unroll
    for (int reg = 0; reg < 4; reg++) {
        float mean = s[reg] * (1.f / 64.f);
        float inv = rsqrtf(s2[reg] * (1.f / 64.f) - mean * mean + 1e-8f);
#pragma unroll
        for (int nt = 0; nt < 4; nt++) {
            int col = nt * 16 + ln;
            float u = (tv[nt * 4 + reg] - mean) * inv * fg[col] + fb[col];
            uv[nt * 4 + reg] = u;
            T1[wv][(quad * 4 + reg) * 64 + col] = f2bf(u);
        }
    }
    __syncthreads();
    bf16x8 au0 = ld8(&T1[wv][ln * 64 + quad * 8]);
    bf16x8 au1 = ld8(&T1[wv][ln * 64 + 32 + quad * 8]);
#pragma unroll
    for (int nt = 0; nt < 4; nt++) {
        int col = nt * 16 + ln;
        bf16x8 w0 = ld8(Wt1 + col * 64 + quad * 8);
        bf16x8 w1 = ld8(Wt1 + col * 64 + 32 + quad * 8);
        f32x4 acc = (f32x4){0.f, 0.f, 0.f, 0.f};
        acc = __builtin_amdgcn_mfma_f32_16x16x32_bf16(au0, w0, acc, 0, 0, 0);
        acc = __builtin_amdgcn_mfma_f32_16x16x32_bf16(au1, w1, acc, 0, 0, 0);
        float b1v = b1[col];
#pragma unroll
        for (int reg = 0; reg < 4; reg++)
            T2[wv][(quad * 4 + reg) * 64 + col] = f2bf(fmaxf(acc[reg] + b1v, 0.f));
    }
    __syncthreads();
    bf16x8 ah0 = ld8(&T2[wv][ln * 64 + quad * 8]);
    bf16x8 ah1 = ld8(&T2[wv][ln * 64 + 32 + quad * 8]);
#pragma unroll
    for (int nt = 0; nt < 4; nt++) {
        int col = nt * 16 + ln;
        bf16x8 w0 = ld8(Wt2 + col * 64 + quad * 8);
        bf16x8 w1 = ld8(Wt2 + col * 64 + 32 + quad * 8);
        f32x4 acc = (f32x4){0.f, 0.f, 0.f, 0.f};
        acc = __builtin_amdgcn_mfma_f32_16x16x32_bf16(ah0, w0, acc, 0, 0, 0);
        acc = __builtin_amdgcn_mfma_f32_16x16x32_bf16(ah1, w1, acc, 0, 0, 0);
        float b2v = b2[col];
#pragma unroll
        for (int reg = 0; reg < 4; reg++) {
            int r = m0 + quad * 4 + reg;
            float v = acc[reg] + b2v + uv[nt * 4 + reg];
            v *= (tseq[r] != 0) ? 1.f : 0.f;
            qout[(long)r * 64 + col] = f2bf(v);
        }
    }
}

// ---------- final LN + logits ----------
__global__ __launch_bounds__(256) void logits_kernel(
    const __bf16* __restrict__ q, const int* __restrict__ pos, const int* __restrict__ neg,
    const float* __restrict__ item, const float* __restrict__ lg, const float* __restrict__ lb,
    float* __restrict__ out)
{
    int row = blockIdx.x * 4 + (threadIdx.x >> 6);
    int lane = threadIdx.x & 63;
    float v = bf2f(q[(long)row * Hc + lane]);
    float s = v, s2 = v * v;
#pragma unroll
    for (int m = 1; m <= 32; m <<= 1) { s += __shfl_xor(s, m, 64); s2 += __shfl_xor(s2, m, 64); }
    float mean = s * (1.f / 64.f);
    float inv = rsqrtf(s2 * (1.f / 64.f) - mean * mean + 1e-8f);
    float lf = (v - mean) * inv * lg[lane] + lb[lane];
    long p = pos[row], n = neg[row];
    float dp = lf * item[p * Hc + lane];
    float dn = lf * item[n * Hc + lane];
#pragma unroll
    for (int m = 1; m <= 32; m <<= 1) { dp += __shfl_xor(dp, m, 64); dn += __shfl_xor(dn, m, 64); }
    if (lane == 0) { out[row] = dp; out[NROWS + row] = dn; }
}

// ---------- launch ----------
extern "C" void kernel_launch(void* const* d_in, const int* in_sizes, int n_in,
                              void* d_out, int out_size, void* d_ws, size_t ws_size,
                              hipStream_t stream)
{
    const int* tseq = (const int*)d_in[0];
    const int* pos  = (const int*)d_in[1];
    const int* neg  = (const int*)d_in[2];
    const float* rev   = (const float*)d_in[3];
    const float* meta  = (const float*)d_in[4];
    const float* item  = (const float*)d_in[5];
    const float* pe    = (const float*)d_in[6];
    const float* featW = (const float*)d_in[7];
    const float* featb = (const float*)d_in[8];
    const float* rg    = (const float*)d_in[9];
    const float* rb    = (const float*)d_in[10];
    const float* Wq = (const float*)d_in[11]; const float* Wk = (const float*)d_in[12];
    const float* Wv = (const float*)d_in[13]; const float* Wpq = (const float*)d_in[14];
    const float* Wpk = (const float*)d_in[15]; const float* Wfq = (const float*)d_in[16];
    const float* Wfk = (const float*)d_in[17]; const float* Wo = (const float*)d_in[18];
    const float* W1 = (const float*)d_in[19]; const float* W2 = (const float*)d_in[20];
    const float* bq = (const float*)d_in[21]; const float* bk = (const float*)d_in[22];
    const float* bv = (const float*)d_in[23]; const float* bpq = (const float*)d_in[24];
    const float* bpk = (const float*)d_in[25]; const float* bfq = (const float*)d_in[26];
    const float* bfk = (const float*)d_in[27]; const float* bo = (const float*)d_in[28];
    const float* b1 = (const float*)d_in[29]; const float* b2 = (const float*)d_in[30];
    const float* ag = (const float*)d_in[31]; const float* ab = (const float*)d_in[32];
    const float* fg = (const float*)d_in[33]; const float* fb = (const float*)d_in[34];
    const float* lg = (const float*)d_in[35]; const float* lb = (const float*)d_in[36];
    float* out = (float*)d_out;

    __bf16* wsb = (__bf16*)d_ws;
    const size_t F = (size_t)NROWS * Hc;
    __bf16* feat = wsb;
    __bf16* q    = wsb + 1 * F;
    __bf16* Qn   = wsb + 2 * F;
    __bf16* qp   = wsb + 3 * F;   // also ctx (phase-disjoint rows)
    __bf16* kp   = wsb + 4 * F;
    __bf16* vp   = wsb + 5 * F;
    __bf16* fqp  = wsb + 6 * F;
    __bf16* fkp  = wsb + 7 * F;
    __bf16* pqp  = wsb + 8 * F;                    // [2][200][64]
    __bf16* pkp  = pqp + 2 * Sc * Hc;
    __bf16* featWt = pkp + 2 * Sc * Hc;            // [64][768]
    __bf16* Wt     = featWt + Ec * Hc;             // [10][2][64][64]

    const int PB = NROWS / 64;     // 800
    const int LB = NROWS / 4;      // 12800

    wconv_kernel<<<512, 256, 0, stream>>>(featW, Wq, Wk, Wv, Wpq, Wpk, Wfq, Wfk, Wo, W1, W2,
                                          featWt, Wt);
    feat_kernel<<<PB, 256, 0, stream>>>(tseq, rev, meta, featWt, featb, rg, rb, item, feat, q);
    pe_kernel<<<8, 256, 0, stream>>>(pe, Wt, bpq, bpk, pqp, pkp);

    for (int i = 0; i < 2; i++) {
        qkvf_kernel<<<PB, 256, 0, stream>>>(q, feat, Wt, i,
                                            bq, bk, bv, bfq, bfk, ag, ab,
                                            Qn, qp, kp, vp, fqp, fkp);
        attn_kernel<<<dim3(Bc * 2, 7), 256, 0, stream>>>(qp, kp, vp,
                                                         pqp + i * Sc * Hc, pkp + i * Sc * Hc,
                                                         fqp, fkp, /*ctx=*/qp);
        ffn_kernel<<<PB, 256, 0, stream>>>(qp, Qn,
                                           Wt + 7 * 8192 + i * 4096,
                                           Wt + 8 * 8192 + i * 4096,
                                           Wt + 9 * 8192 + i * 4096,
                                           bo + i * 64, b1 + i * 64, b2 + i * 64,
                                           fg + i * 64, fb + i * 64, tseq, q);
    }
    logits_kernel<<<LB, 256, 0, stream>>>(q, pos, neg, item, lg, lb, out);
}